// Round 1
// baseline (312.668 us; speedup 1.0000x reference)
//
#include <hip/hip_runtime.h>
#include <hip/hip_bf16.h>

#define Bb 4
#define Ss 2048
#define Ee 512
#define Hh 8
#define DKk 64
// M = Bb*Ss = 8192

typedef __bf16 bf16_t;
typedef bf16_t bf16x8 __attribute__((ext_vector_type(8)));
typedef float f32x4 __attribute__((ext_vector_type(4)));

#define MFMA16(a, b, c) __builtin_amdgcn_mfma_f32_16x16x32_bf16(a, b, c, 0, 0, 0)

static __device__ __forceinline__ bf16_t f2bf(float f) { return (bf16_t)f; }

// ---------------------------------------------------------------------------
// Pack: transpose + fp32->bf16 weights.
//  Wt[mat][n = h*64+d][k = e] = W_mat[h][e][d]   (mat = 0,1,2 : Wq,Wk,Wv)
//  Wft[f][e] = Wf[e][f]
// grid (8, 32), 256 threads. y<24: mat=y>>3, h=y&7 (src 512x64, rowstride 64).
// y>=24: Wf tile col (y-24).
// ---------------------------------------------------------------------------
__global__ __launch_bounds__(256) void pack_weights_k(
    const float* __restrict__ Wq, const float* __restrict__ Wk,
    const float* __restrict__ Wv, const float* __restrict__ Wf,
    bf16_t* __restrict__ Wt, bf16_t* __restrict__ Wft) {
  __shared__ float tile[64][65];
  int t = threadIdx.x;
  int y = blockIdx.y;
  const float* sp;
  bf16_t* dp;
  int sR, r0, c0;
  if (y < 24) {
    int mat = y >> 3, h = y & 7;
    const float* W = (mat == 0) ? Wq : ((mat == 1) ? Wk : Wv);
    sp = W + (size_t)h * (Ee * DKk);
    sR = 64;
    dp = Wt + (size_t)mat * (Ee * Ee) + (size_t)(h * 64) * Ee;
    r0 = blockIdx.x * 64;
    c0 = 0;
  } else {
    sp = Wf;
    sR = 512;
    dp = Wft;
    r0 = blockIdx.x * 64;
    c0 = (y - 24) * 64;
  }
  int lr = t >> 2, seg = t & 3;
  const float* sprow = sp + (size_t)(r0 + lr) * sR + c0 + seg * 16;
  float4 f0 = ((const float4*)sprow)[0];
  float4 f1 = ((const float4*)sprow)[1];
  float4 f2 = ((const float4*)sprow)[2];
  float4 f3 = ((const float4*)sprow)[3];
  tile[lr][seg * 16 + 0] = f0.x;  tile[lr][seg * 16 + 1] = f0.y;
  tile[lr][seg * 16 + 2] = f0.z;  tile[lr][seg * 16 + 3] = f0.w;
  tile[lr][seg * 16 + 4] = f1.x;  tile[lr][seg * 16 + 5] = f1.y;
  tile[lr][seg * 16 + 6] = f1.z;  tile[lr][seg * 16 + 7] = f1.w;
  tile[lr][seg * 16 + 8] = f2.x;  tile[lr][seg * 16 + 9] = f2.y;
  tile[lr][seg * 16 + 10] = f2.z; tile[lr][seg * 16 + 11] = f2.w;
  tile[lr][seg * 16 + 12] = f3.x; tile[lr][seg * 16 + 13] = f3.y;
  tile[lr][seg * 16 + 14] = f3.z; tile[lr][seg * 16 + 15] = f3.w;
  __syncthreads();
  // write: dest row (c0+lr), cols r0 + seg*16 .. +16 ; val = tile[col][lr]
  bf16x8 o0, o1;
#pragma unroll
  for (int i = 0; i < 8; i++) {
    o0[i] = f2bf(tile[seg * 16 + i][lr]);
    o1[i] = f2bf(tile[seg * 16 + 8 + i][lr]);
  }
  bf16_t* dst = dp + (size_t)(c0 + lr) * Ee + r0 + seg * 16;
  *(bf16x8*)dst = o0;
  *(bf16x8*)(dst + 8) = o1;
}

// ---------------------------------------------------------------------------
// Projection GEMM: out[b,h,s,d] = sum_e X[b,s,e]*W[h,e,d] + bias[h,d]
// A (fp32, cvt->bf16 in staging): [8192][512], B = Wt[z] (bf16, [N][K]).
// 128x128 tile, BK=32, 4 waves of 64x64. grid (4, 64, 3).
// ---------------------------------------------------------------------------
__global__ __launch_bounds__(256) void proj_gemm_k(
    const float* __restrict__ Qi, const float* __restrict__ Ki,
    const float* __restrict__ Vi, const bf16_t* __restrict__ Wt,
    const float* __restrict__ bq, const float* __restrict__ bk,
    const float* __restrict__ bv, bf16_t* __restrict__ qkv) {
  __shared__ bf16_t As[128][40];
  __shared__ bf16_t Bs[128][40];
  int t = threadIdx.x;
  int zb = blockIdx.z;
  const float* A = (zb == 0) ? Qi : ((zb == 1) ? Ki : Vi);
  const bf16_t* Bm = Wt + (size_t)zb * (Ee * Ee);
  const float* bias = (zb == 0) ? bq : ((zb == 1) ? bk : bv);
  bf16_t* Outp = qkv + (size_t)zb * ((size_t)Bb * Hh * Ss * DKk);
  int m0 = blockIdx.y * 128;
  int n0 = blockIdx.x * 128;
  int lane = t & 63, w = t >> 6;
  int wr = w >> 1, wc = w & 1;
  int rsel = lane & 15, grp = lane >> 4;
  int ar = t >> 1, ak = (t & 1) * 16;

  f32x4 acc[4][4];
#pragma unroll
  for (int mi = 0; mi < 4; mi++)
#pragma unroll
    for (int ni = 0; ni < 4; ni++) acc[mi][ni] = (f32x4){0.f, 0.f, 0.f, 0.f};

  for (int k0 = 0; k0 < Ee; k0 += 32) {
    // stage A (fp32 -> bf16)
    const float* aprow = A + (size_t)(m0 + ar) * Ee + k0 + ak;
    float4 fa0 = ((const float4*)aprow)[0];
    float4 fa1 = ((const float4*)aprow)[1];
    float4 fa2 = ((const float4*)aprow)[2];
    float4 fa3 = ((const float4*)aprow)[3];
    bf16x8 p0, p1;
    p0[0] = f2bf(fa0.x); p0[1] = f2bf(fa0.y); p0[2] = f2bf(fa0.z); p0[3] = f2bf(fa0.w);
    p0[4] = f2bf(fa1.x); p0[5] = f2bf(fa1.y); p0[6] = f2bf(fa1.z); p0[7] = f2bf(fa1.w);
    p1[0] = f2bf(fa2.x); p1[1] = f2bf(fa2.y); p1[2] = f2bf(fa2.z); p1[3] = f2bf(fa2.w);
    p1[4] = f2bf(fa3.x); p1[5] = f2bf(fa3.y); p1[6] = f2bf(fa3.z); p1[7] = f2bf(fa3.w);
    *(bf16x8*)&As[ar][ak] = p0;
    *(bf16x8*)&As[ar][ak + 8] = p1;
    // stage B (bf16 copy)
    const bf16x8* bprow = (const bf16x8*)(Bm + (size_t)(n0 + ar) * Ee + k0 + ak);
    *(bf16x8*)&Bs[ar][ak] = bprow[0];
    *(bf16x8*)&Bs[ar][ak + 8] = bprow[1];
    __syncthreads();

    bf16x8 af[4], bfr[4];
#pragma unroll
    for (int mi = 0; mi < 4; mi++)
      af[mi] = *(const bf16x8*)&As[wr * 64 + mi * 16 + rsel][grp * 8];
#pragma unroll
    for (int ni = 0; ni < 4; ni++)
      bfr[ni] = *(const bf16x8*)&Bs[wc * 64 + ni * 16 + rsel][grp * 8];
#pragma unroll
    for (int mi = 0; mi < 4; mi++)
#pragma unroll
      for (int ni = 0; ni < 4; ni++)
        acc[mi][ni] = MFMA16(af[mi], bfr[ni], acc[mi][ni]);
    __syncthreads();
  }

  // epilogue: scatter to [b*H+h][s][d] bf16, add bias
#pragma unroll
  for (int mi = 0; mi < 4; mi++) {
    int mbase = m0 + wr * 64 + mi * 16 + grp * 4;
#pragma unroll
    for (int ni = 0; ni < 4; ni++) {
      int n = n0 + wc * 64 + ni * 16 + rsel;
      int h = n >> 6, d = n & 63;
      float bval = bias[n];
#pragma unroll
      for (int r = 0; r < 4; r++) {
        int mm = mbase + r;
        int b = mm >> 11, s = mm & 2047;
        Outp[(((size_t)(b * Hh + h)) * Ss + s) * DKk + d] =
            f2bf(acc[mi][ni][r] + bval);
      }
    }
  }
}

// ---------------------------------------------------------------------------
// Flash attention. qkv: [3][B*H][S][64] bf16. zout: [B][S][E] bf16 (heads concat)
// grid (32 qblocks, 32 bh), 256 threads = 4 waves x 16 q-rows. KV tile = 64.
// Swapped QK^T: ST = mfma(K, Q) -> ST[key][q]; softmax per q (lane-column);
// P routed via LDS into A-layout; V staged transposed in LDS.
// ---------------------------------------------------------------------------
__global__ __launch_bounds__(256) void attn_k(
    const bf16_t* __restrict__ qkv, bf16_t* __restrict__ zout) {
  const size_t HS = (size_t)Bb * Hh * Ss * DKk;  // 4,194,304
  int bh = blockIdx.y;
  int qblk = blockIdx.x;
  int t = threadIdx.x, lane = t & 63, w = t >> 6;
  int rsel = lane & 15, grp = lane >> 4;
  const bf16_t* qp = qkv + (size_t)bh * (Ss * DKk);
  const bf16_t* kp = qp + HS;
  const bf16_t* vp = qp + 2 * HS;
  int qbase = qblk * 64 + w * 16;

  __shared__ bf16_t Vt[64][72];      // V^T: [dk][key]
  __shared__ bf16_t Pl[4][16][72];   // per-wave P: [q][key]

  // Q B-fragments (hoisted): B[k=dk][col=q] -> Q[qbase+rsel][ks*32 + grp*8 + e]
  bf16x8 qf0 = *(const bf16x8*)(qp + (size_t)(qbase + rsel) * DKk + grp * 8);
  bf16x8 qf1 = *(const bf16x8*)(qp + (size_t)(qbase + rsel) * DKk + 32 + grp * 8);

  float m_run = -3e38f, l_run = 0.f;
  f32x4 acc[4];
#pragma unroll
  for (int n = 0; n < 4; n++) acc[n] = (f32x4){0.f, 0.f, 0.f, 0.f};

  for (int t0 = 0; t0 < Ss; t0 += 64) {
    // cooperative stage of V^T tile
#pragma unroll
    for (int j = 0; j < 2; j++) {
      int slot = t * 2 + j;            // 0..511
      int kk = slot >> 3, seg = slot & 7;
      bf16x8 vv = *(const bf16x8*)(vp + (size_t)(t0 + kk) * DKk + seg * 8);
#pragma unroll
      for (int e = 0; e < 8; e++) Vt[seg * 8 + e][kk] = vv[e];
    }

    // swapped QK^T: per mf, A = K rows [16 key][32 dk]
    float sv[16];
    float pmax = -3e38f;
#pragma unroll
    for (int mf = 0; mf < 4; mf++) {
      const bf16_t* krow = kp + (size_t)(t0 + mf * 16 + rsel) * DKk;
      bf16x8 kf0 = *(const bf16x8*)(krow + grp * 8);
      bf16x8 kf1 = *(const bf16x8*)(krow + 32 + grp * 8);
      f32x4 c = (f32x4){0.f, 0.f, 0.f, 0.f};
      c = MFMA16(kf0, qf0, c);
      c = MFMA16(kf1, qf1, c);
#pragma unroll
      for (int r = 0; r < 4; r++) {
        float v = c[r] * 0.125f;
        sv[mf * 4 + r] = v;
        pmax = fmaxf(pmax, v);
      }
    }
    // reduce max over the 4 lane-groups holding this q-column
    pmax = fmaxf(pmax, __shfl_xor(pmax, 16));
    pmax = fmaxf(pmax, __shfl_xor(pmax, 32));
    float m_new = fmaxf(m_run, pmax);
    float sc = __expf(m_run - m_new);
    float psum = 0.f;
    bf16_t pb[16];
#pragma unroll
    for (int i = 0; i < 16; i++) {
      float p = __expf(sv[i] - m_new);
      psum += p;
      pb[i] = f2bf(p);
    }
    psum += __shfl_xor(psum, 16);
    psum += __shfl_xor(psum, 32);
    l_run = l_run * sc + psum;
    m_run = m_new;
    // rescale ctx accumulator rows (row q_local = grp*4+r -> stats live at lane q_local)
    float scr[4];
#pragma unroll
    for (int r = 0; r < 4; r++) scr[r] = __shfl(sc, grp * 4 + r);
#pragma unroll
    for (int n = 0; n < 4; n++)
#pragma unroll
      for (int r = 0; r < 4; r++) acc[n][r] *= scr[r];
    // write P (this wave's private region)
#pragma unroll
    for (int mf = 0; mf < 4; mf++)
#pragma unroll
      for (int r = 0; r < 4; r++)
        Pl[w][rsel][mf * 16 + grp * 4 + r] = pb[mf * 4 + r];
    __syncthreads();

    // PV: ctx += P * V
    bf16x8 pa0 = *(const bf16x8*)&Pl[w][rsel][grp * 8];
    bf16x8 pa1 = *(const bf16x8*)&Pl[w][rsel][32 + grp * 8];
#pragma unroll
    for (int n = 0; n < 4; n++) {
      bf16x8 vb0 = *(const bf16x8*)&Vt[n * 16 + rsel][grp * 8];
      bf16x8 vb1 = *(const bf16x8*)&Vt[n * 16 + rsel][32 + grp * 8];
      acc[n] = MFMA16(pa0, vb0, acc[n]);
      acc[n] = MFMA16(pa1, vb1, acc[n]);
    }
    __syncthreads();
  }

  // finalize: divide by l, write z[b][s][h*64 + dk]
  float li[4];
#pragma unroll
  for (int r = 0; r < 4; r++) {
    float ls = __shfl(l_run, grp * 4 + r);
    li[r] = 1.f / ls;
  }
  int b = bh >> 3, h = bh & 7;
#pragma unroll
  for (int n = 0; n < 4; n++)
#pragma unroll
    for (int r = 0; r < 4; r++) {
      int srow = qbase + grp * 4 + r;
      zout[((size_t)(b * Ss + srow)) * Ee + h * 64 + n * 16 + rsel] =
          f2bf(acc[n][r] * li[r]);
    }
}

// ---------------------------------------------------------------------------
// Final GEMM: x[m][n] = sum_e z[m][e]*Wf[e][n] + bf[n] + Qres[m][n]  (fp32 out)
// A = z (bf16), B = Wft (bf16, [N][K]). grid (4, 64).
// ---------------------------------------------------------------------------
__global__ __launch_bounds__(256) void final_gemm_k(
    const bf16_t* __restrict__ z, const bf16_t* __restrict__ Wft,
    const float* __restrict__ bfb, const float* __restrict__ Qres,
    float* __restrict__ x) {
  __shared__ bf16_t As[128][40];
  __shared__ bf16_t Bs[128][40];
  int t = threadIdx.x;
  int m0 = blockIdx.y * 128;
  int n0 = blockIdx.x * 128;
  int lane = t & 63, w = t >> 6;
  int wr = w >> 1, wc = w & 1;
  int rsel = lane & 15, grp = lane >> 4;
  int ar = t >> 1, ak = (t & 1) * 16;

  f32x4 acc[4][4];
#pragma unroll
  for (int mi = 0; mi < 4; mi++)
#pragma unroll
    for (int ni = 0; ni < 4; ni++) acc[mi][ni] = (f32x4){0.f, 0.f, 0.f, 0.f};

  for (int k0 = 0; k0 < Ee; k0 += 32) {
    const bf16x8* aprow = (const bf16x8*)(z + (size_t)(m0 + ar) * Ee + k0 + ak);
    *(bf16x8*)&As[ar][ak] = aprow[0];
    *(bf16x8*)&As[ar][ak + 8] = aprow[1];
    const bf16x8* bprow = (const bf16x8*)(Wft + (size_t)(n0 + ar) * Ee + k0 + ak);
    *(bf16x8*)&Bs[ar][ak] = bprow[0];
    *(bf16x8*)&Bs[ar][ak + 8] = bprow[1];
    __syncthreads();

    bf16x8 af[4], bfr[4];
#pragma unroll
    for (int mi = 0; mi < 4; mi++)
      af[mi] = *(const bf16x8*)&As[wr * 64 + mi * 16 + rsel][grp * 8];
#pragma unroll
    for (int ni = 0; ni < 4; ni++)
      bfr[ni] = *(const bf16x8*)&Bs[wc * 64 + ni * 16 + rsel][grp * 8];
#pragma unroll
    for (int mi = 0; mi < 4; mi++)
#pragma unroll
      for (int ni = 0; ni < 4; ni++)
        acc[mi][ni] = MFMA16(af[mi], bfr[ni], acc[mi][ni]);
    __syncthreads();
  }

#pragma unroll
  for (int mi = 0; mi < 4; mi++) {
    int mbase = m0 + wr * 64 + mi * 16 + grp * 4;
#pragma unroll
    for (int ni = 0; ni < 4; ni++) {
      int n = n0 + wc * 64 + ni * 16 + rsel;
      float bval = bfb[n];
#pragma unroll
      for (int r = 0; r < 4; r++) {
        int mm = mbase + r;
        x[(size_t)mm * Ee + n] = acc[mi][ni][r] + bval + Qres[(size_t)mm * Ee + n];
      }
    }
  }
}

// ---------------------------------------------------------------------------
// LayerNorm over E=512. One wave per row. grid (2048), 256 threads.
// ---------------------------------------------------------------------------
__global__ __launch_bounds__(256) void ln_k(
    const float* __restrict__ x, const float* __restrict__ gamma,
    const float* __restrict__ beta, float* __restrict__ out) {
  int row = blockIdx.x * 4 + (threadIdx.x >> 6);
  int lane = threadIdx.x & 63;
  const float* xr = x + (size_t)row * Ee;
  float4 v0 = *(const float4*)(xr + lane * 8);
  float4 v1 = *(const float4*)(xr + lane * 8 + 4);
  float s = v0.x + v0.y + v0.z + v0.w + v1.x + v1.y + v1.z + v1.w;
  float ss = v0.x * v0.x + v0.y * v0.y + v0.z * v0.z + v0.w * v0.w +
             v1.x * v1.x + v1.y * v1.y + v1.z * v1.z + v1.w * v1.w;
#pragma unroll
  for (int off = 32; off >= 1; off >>= 1) {
    s += __shfl_xor(s, off);
    ss += __shfl_xor(ss, off);
  }
  float mean = s * (1.f / 512.f);
  float var = ss * (1.f / 512.f) - mean * mean;
  float inv = rsqrtf(var + 1e-5f);
  float4 g0 = *(const float4*)(gamma + lane * 8);
  float4 g1 = *(const float4*)(gamma + lane * 8 + 4);
  float4 b0 = *(const float4*)(beta + lane * 8);
  float4 b1 = *(const float4*)(beta + lane * 8 + 4);
  float4 o0, o1;
  o0.x = (v0.x - mean) * inv * g0.x + b0.x;
  o0.y = (v0.y - mean) * inv * g0.y + b0.y;
  o0.z = (v0.z - mean) * inv * g0.z + b0.z;
  o0.w = (v0.w - mean) * inv * g0.w + b0.w;
  o1.x = (v1.x - mean) * inv * g1.x + b1.x;
  o1.y = (v1.y - mean) * inv * g1.y + b1.y;
  o1.z = (v1.z - mean) * inv * g1.z + b1.z;
  o1.w = (v1.w - mean) * inv * g1.w + b1.w;
  float* orow = out + (size_t)row * Ee;
  *(float4*)(orow + lane * 8) = o0;
  *(float4*)(orow + lane * 8 + 4) = o1;
}

// ---------------------------------------------------------------------------
extern "C" void kernel_launch(void* const* d_in, const int* in_sizes, int n_in,
                              void* d_out, int out_size, void* d_ws, size_t ws_size,
                              hipStream_t stream) {
  const float* Q = (const float*)d_in[0];
  const float* K = (const float*)d_in[1];
  const float* V = (const float*)d_in[2];
  const float* Wq = (const float*)d_in[3];
  const float* bq = (const float*)d_in[4];
  const float* Wk = (const float*)d_in[5];
  const float* bk = (const float*)d_in[6];
  const float* Wv = (const float*)d_in[7];
  const float* bv = (const float*)d_in[8];
  const float* Wf = (const float*)d_in[9];
  const float* bfb = (const float*)d_in[10];
  const float* gamma = (const float*)d_in[11];
  const float* beta = (const float*)d_in[12];
  float* out = (float*)d_out;

  bf16_t* Wt = (bf16_t*)d_ws;                       // 3*512*512
  bf16_t* Wft = Wt + 3 * Ee * Ee;                   // 512*512
  bf16_t* qkv = Wft + Ee * Ee;                      // 3*4,194,304
  bf16_t* z = qkv + (size_t)3 * Bb * Hh * Ss * DKk; // 4,194,304
  float* x = (float*)(z + (size_t)Bb * Ss * Ee);    // 4,194,304 fp32

  pack_weights_k<<<dim3(8, 32), dim3(256), 0, stream>>>(Wq, Wk, Wv, Wf, Wt, Wft);
  proj_gemm_k<<<dim3(4, 64, 3), dim3(256), 0, stream>>>(Q, K, V, Wt, bq, bk, bv, qkv);
  attn_k<<<dim3(32, 32), dim3(256), 0, stream>>>(qkv, z);
  final_gemm_k<<<dim3(4, 64), dim3(256), 0, stream>>>(z, Wft, bfb, Q, x);
  ln_k<<<dim3(2048), dim3(256), 0, stream>>>(x, gamma, beta, out);
}

// Round 3
// 211.244 us; speedup vs baseline: 1.4801x; 1.4801x over previous
//
#include <hip/hip_runtime.h>
#include <hip/hip_bf16.h>

#define Bb 4
#define Ss 2048
#define Ee 512
#define Hh 8
#define DKk 64
// M = Bb*Ss = 8192

typedef __bf16 bf16_t;
typedef bf16_t bf16x8 __attribute__((ext_vector_type(8)));
typedef bf16_t bf16x4 __attribute__((ext_vector_type(4)));
typedef float f32x4 __attribute__((ext_vector_type(4)));
typedef float f32x16 __attribute__((ext_vector_type(16)));

#define MFMA16(a, b, c) __builtin_amdgcn_mfma_f32_16x16x32_bf16(a, b, c, 0, 0, 0)
#define MFMA32(a, b, c) __builtin_amdgcn_mfma_f32_32x32x16_bf16(a, b, c, 0, 0, 0)

#define GLOAD16(src, dst)                                          \
  __builtin_amdgcn_global_load_lds(                                \
      (const __attribute__((address_space(1))) void*)(src),        \
      (__attribute__((address_space(3))) void*)(dst), 16, 0, 0)

static __device__ __forceinline__ bf16_t f2bf(float f) { return (bf16_t)f; }

static __device__ __forceinline__ float fast_exp2(float x) {
#if __has_builtin(__builtin_amdgcn_exp2f)
  return __builtin_amdgcn_exp2f(x);
#else
  return exp2f(x);
#endif
}

static __device__ __forceinline__ unsigned cvtpk(float lo, float hi) {
  unsigned r;
  asm("v_cvt_pk_bf16_f32 %0, %1, %2" : "=v"(r) : "v"(lo), "v"(hi));
  return r;
}
// v_permlane32_swap_b32: A[32:63] <-> B[0:31].
static __device__ __forceinline__ void plswap(unsigned& a, unsigned& b) {
  asm("v_permlane32_swap_b32 %0, %1" : "+v"(a), "+v"(b));
}

// ---------------------------------------------------------------------------
// fp32 -> bf16 convert: Q,K,V -> Qb,Kb,Vb (contiguous at dst).
// ---------------------------------------------------------------------------
__global__ __launch_bounds__(256) void cvt_k(const float* __restrict__ Q,
                                             const float* __restrict__ K,
                                             const float* __restrict__ V,
                                             bf16_t* __restrict__ dst) {
  int which = blockIdx.x >> 11;
  int bi = blockIdx.x & 2047;
  const float* src = (which == 0) ? Q : ((which == 1) ? K : V);
  bf16_t* d = dst + (size_t)which * ((size_t)Bb * Ss * Ee);
  size_t idx = ((size_t)bi * 256 + threadIdx.x) * 8;
  float4 a = *(const float4*)(src + idx);
  float4 b = *(const float4*)(src + idx + 4);
  bf16x8 o;
  o[0] = f2bf(a.x); o[1] = f2bf(a.y); o[2] = f2bf(a.z); o[3] = f2bf(a.w);
  o[4] = f2bf(b.x); o[5] = f2bf(b.y); o[6] = f2bf(b.z); o[7] = f2bf(b.w);
  *(bf16x8*)(d + idx) = o;
}

// ---------------------------------------------------------------------------
// Pack: transpose + fp32->bf16 weights.
//  Wt[mat][n = h*64+d][k = e] = W_mat[h][e][d]   (mat = 0,1,2 : Wq,Wk,Wv)
//  Wft[f][e] = Wf[e][f]
// ---------------------------------------------------------------------------
__global__ __launch_bounds__(256) void pack_weights_k(
    const float* __restrict__ Wq, const float* __restrict__ Wk,
    const float* __restrict__ Wv, const float* __restrict__ Wf,
    bf16_t* __restrict__ Wt, bf16_t* __restrict__ Wft) {
  __shared__ float tile[64][65];
  int t = threadIdx.x;
  int y = blockIdx.y;
  const float* sp;
  bf16_t* dp;
  int sR, r0, c0;
  if (y < 24) {
    int mat = y >> 3, h = y & 7;
    const float* W = (mat == 0) ? Wq : ((mat == 1) ? Wk : Wv);
    sp = W + (size_t)h * (Ee * DKk);
    sR = 64;
    dp = Wt + (size_t)mat * (Ee * Ee) + (size_t)(h * 64) * Ee;
    r0 = blockIdx.x * 64;
    c0 = 0;
  } else {
    sp = Wf;
    sR = 512;
    dp = Wft;
    r0 = blockIdx.x * 64;
    c0 = (y - 24) * 64;
  }
  int lr = t >> 2, seg = t & 3;
  const float* sprow = sp + (size_t)(r0 + lr) * sR + c0 + seg * 16;
  float4 f0 = ((const float4*)sprow)[0];
  float4 f1 = ((const float4*)sprow)[1];
  float4 f2 = ((const float4*)sprow)[2];
  float4 f3 = ((const float4*)sprow)[3];
  tile[lr][seg * 16 + 0] = f0.x;  tile[lr][seg * 16 + 1] = f0.y;
  tile[lr][seg * 16 + 2] = f0.z;  tile[lr][seg * 16 + 3] = f0.w;
  tile[lr][seg * 16 + 4] = f1.x;  tile[lr][seg * 16 + 5] = f1.y;
  tile[lr][seg * 16 + 6] = f1.z;  tile[lr][seg * 16 + 7] = f1.w;
  tile[lr][seg * 16 + 8] = f2.x;  tile[lr][seg * 16 + 9] = f2.y;
  tile[lr][seg * 16 + 10] = f2.z; tile[lr][seg * 16 + 11] = f2.w;
  tile[lr][seg * 16 + 12] = f3.x; tile[lr][seg * 16 + 13] = f3.y;
  tile[lr][seg * 16 + 14] = f3.z; tile[lr][seg * 16 + 15] = f3.w;
  __syncthreads();
  bf16x8 o0, o1;
#pragma unroll
  for (int i = 0; i < 8; i++) {
    o0[i] = f2bf(tile[seg * 16 + i][lr]);
    o1[i] = f2bf(tile[seg * 16 + 8 + i][lr]);
  }
  bf16_t* dst = dp + (size_t)(c0 + lr) * Ee + r0 + seg * 16;
  *(bf16x8*)dst = o0;
  *(bf16x8*)(dst + 8) = o1;
}

// ---------------------------------------------------------------------------
// Projection GEMM (operand-swapped): D[n][m] = sum_e Wt[n][e] * Xb[m][e]
// 128x128 tile, BK=64, global_load_lds + XOR-chunk swizzle (source side).
// Epilogue: qkv[z][b*H+h][s][d..d+4] = (acc + bias) * scl, 8B stores.
// ---------------------------------------------------------------------------
__global__ __launch_bounds__(256) void proj_gemm_k(
    const bf16_t* __restrict__ Xb3, const bf16_t* __restrict__ Wt,
    const float* __restrict__ bq, const float* __restrict__ bk,
    const float* __restrict__ bv, bf16_t* __restrict__ qkv) {
  __shared__ bf16_t As[128 * 64];
  __shared__ bf16_t Bs[128 * 64];
  const int t = threadIdx.x;
  const int zb = blockIdx.z;
  const bf16_t* Ap = Wt + (size_t)zb * (Ee * Ee);
  const bf16_t* Bp = Xb3 + (size_t)zb * ((size_t)Bb * Ss * Ee);
  const float* bias = (zb == 0) ? bq : ((zb == 1) ? bk : bv);
  bf16_t* Outp = qkv + (size_t)zb * ((size_t)Bb * Hh * Ss * DKk);
  const float scl = (zb == 0) ? 0.18033688f : 1.0f;  // 0.125 * log2(e) for q
  const int n0 = blockIdx.x * 128;
  const int m0 = blockIdx.y * 128;
  const int lane = t & 63, w = t >> 6;
  const int wn = w >> 1, wm = w & 1;
  const int rsel = lane & 15, grp = lane >> 4;
  const int wbase = (t & ~63);

  f32x4 acc[4][4];
#pragma unroll
  for (int ni = 0; ni < 4; ni++)
#pragma unroll
    for (int mi = 0; mi < 4; mi++) acc[ni][mi] = (f32x4){0.f, 0.f, 0.f, 0.f};

  for (int k0 = 0; k0 < Ee; k0 += 64) {
#pragma unroll
    for (int i = 0; i < 4; i++) {
      int slot = i * 256 + t;
      int row = slot >> 3;
      int g = (slot & 7) ^ (row & 7);
      GLOAD16(Ap + (size_t)(n0 + row) * Ee + k0 + g * 8,
              As + (size_t)(i * 256 + wbase) * 8);
      GLOAD16(Bp + (size_t)(m0 + row) * Ee + k0 + g * 8,
              Bs + (size_t)(i * 256 + wbase) * 8);
    }
    __syncthreads();
#pragma unroll
    for (int kk = 0; kk < 2; kk++) {
      bf16x8 af[4], bff[4];
#pragma unroll
      for (int ni = 0; ni < 4; ni++) {
        int arow = wn * 64 + ni * 16 + rsel;
        int c = ((kk * 4 + grp) ^ (arow & 7)) * 8;
        af[ni] = *(const bf16x8*)&As[arow * 64 + c];
      }
#pragma unroll
      for (int mi = 0; mi < 4; mi++) {
        int brow = wm * 64 + mi * 16 + rsel;
        int c = ((kk * 4 + grp) ^ (brow & 7)) * 8;
        bff[mi] = *(const bf16x8*)&Bs[brow * 64 + c];
      }
#pragma unroll
      for (int ni = 0; ni < 4; ni++)
#pragma unroll
        for (int mi = 0; mi < 4; mi++)
          acc[ni][mi] = MFMA16(af[ni], bff[mi], acc[ni][mi]);
    }
    __syncthreads();
  }

#pragma unroll
  for (int ni = 0; ni < 4; ni++) {
    int nb = n0 + wn * 64 + ni * 16 + grp * 4;
    float4 b4 = *(const float4*)(bias + nb);
    const float* b4p = (const float*)&b4;
    int hh = nb >> 6, dd = nb & 63;
#pragma unroll
    for (int mi = 0; mi < 4; mi++) {
      int m = m0 + wm * 64 + mi * 16 + rsel;
      int bI = m >> 11, sI = m & 2047;
      bf16x4 o;
#pragma unroll
      for (int r = 0; r < 4; r++)
        o[r] = f2bf((acc[ni][mi][r] + b4p[r]) * scl);
      *(bf16x4*)(Outp + (((size_t)(bI * Hh + hh)) * Ss + sI) * DKk + dd) = o;
    }
  }
}

// ---------------------------------------------------------------------------
// Final GEMM (operand-swapped): D[f][m] = sum_e Wft[f][e] * z[m][e]
// Epilogue: x[m][f..f+4] = acc + bf + Qres (fp32, 16B stores).
// ---------------------------------------------------------------------------
__global__ __launch_bounds__(256) void final_gemm_k(
    const bf16_t* __restrict__ zin, const bf16_t* __restrict__ Wft,
    const float* __restrict__ bfb, const float* __restrict__ Qres,
    float* __restrict__ x) {
  __shared__ bf16_t As[128 * 64];
  __shared__ bf16_t Bs[128 * 64];
  const int t = threadIdx.x;
  const int n0 = blockIdx.x * 128;
  const int m0 = blockIdx.y * 128;
  const int lane = t & 63, w = t >> 6;
  const int wn = w >> 1, wm = w & 1;
  const int rsel = lane & 15, grp = lane >> 4;
  const int wbase = (t & ~63);

  f32x4 acc[4][4];
#pragma unroll
  for (int ni = 0; ni < 4; ni++)
#pragma unroll
    for (int mi = 0; mi < 4; mi++) acc[ni][mi] = (f32x4){0.f, 0.f, 0.f, 0.f};

  for (int k0 = 0; k0 < Ee; k0 += 64) {
#pragma unroll
    for (int i = 0; i < 4; i++) {
      int slot = i * 256 + t;
      int row = slot >> 3;
      int g = (slot & 7) ^ (row & 7);
      GLOAD16(Wft + (size_t)(n0 + row) * Ee + k0 + g * 8,
              As + (size_t)(i * 256 + wbase) * 8);
      GLOAD16(zin + (size_t)(m0 + row) * Ee + k0 + g * 8,
              Bs + (size_t)(i * 256 + wbase) * 8);
    }
    __syncthreads();
#pragma unroll
    for (int kk = 0; kk < 2; kk++) {
      bf16x8 af[4], bff[4];
#pragma unroll
      for (int ni = 0; ni < 4; ni++) {
        int arow = wn * 64 + ni * 16 + rsel;
        int c = ((kk * 4 + grp) ^ (arow & 7)) * 8;
        af[ni] = *(const bf16x8*)&As[arow * 64 + c];
      }
#pragma unroll
      for (int mi = 0; mi < 4; mi++) {
        int brow = wm * 64 + mi * 16 + rsel;
        int c = ((kk * 4 + grp) ^ (brow & 7)) * 8;
        bff[mi] = *(const bf16x8*)&Bs[brow * 64 + c];
      }
#pragma unroll
      for (int ni = 0; ni < 4; ni++)
#pragma unroll
        for (int mi = 0; mi < 4; mi++)
          acc[ni][mi] = MFMA16(af[ni], bff[mi], acc[ni][mi]);
    }
    __syncthreads();
  }

#pragma unroll
  for (int ni = 0; ni < 4; ni++) {
    int nb = n0 + wn * 64 + ni * 16 + grp * 4;
    float4 b4 = *(const float4*)(bfb + nb);
#pragma unroll
    for (int mi = 0; mi < 4; mi++) {
      int m = m0 + wm * 64 + mi * 16 + rsel;
      float4 q4 = *(const float4*)(Qres + (size_t)m * Ee + nb);
      float4 o;
      o.x = acc[ni][mi][0] + b4.x + q4.x;
      o.y = acc[ni][mi][1] + b4.y + q4.y;
      o.z = acc[ni][mi][2] + b4.z + q4.z;
      o.w = acc[ni][mi][3] + b4.w + q4.w;
      *(float4*)(x + (size_t)m * Ee + nb) = o;
    }
  }
}

// ---------------------------------------------------------------------------
// Flash attention, 32x32 swapped-operand structure.
// 8 waves x 32 q-rows = 256 q/block; grid (8, 32); KV tile = 64.
// q pre-scaled by 0.125*log2(e) -> softmax in exp2 domain.
// ST = mfma(K, Q): lane holds 16 scores per 32-key group for q = lane&31.
// PV swapped: ctxT = mfma(Vt, Pfrag): D[dk][q] -> stats lane-local.
// K, Vt double-buffered in stride-68 LDS; async-stage split (T14).
// ---------------------------------------------------------------------------
__global__ __launch_bounds__(512) void attn_k(const bf16_t* __restrict__ qkv,
                                              bf16_t* __restrict__ zout) {
  const size_t HS = (size_t)Bb * Hh * Ss * DKk;
  __shared__ bf16_t Ks[2][64][68];
  __shared__ bf16_t Vt[2][64][68];
  const int t = threadIdx.x, w = t >> 6, lane = t & 63;
  const int ql = lane & 31, hi = lane >> 5;
  const int bh = blockIdx.y;
  const bf16_t* qp = qkv + (size_t)bh * (Ss * DKk);
  const bf16_t* kp = qp + HS;
  const bf16_t* vp = qp + 2 * HS;
  const int qrow = blockIdx.x * 256 + w * 32 + ql;

  // Q B-fragments (hoisted): k-dim = dk, col = q
  bf16x8 qf0 = *(const bf16x8*)(qp + (size_t)qrow * DKk + 0 + hi * 8);
  bf16x8 qf1 = *(const bf16x8*)(qp + (size_t)qrow * DKk + 16 + hi * 8);
  bf16x8 qf2 = *(const bf16x8*)(qp + (size_t)qrow * DKk + 32 + hi * 8);
  bf16x8 qf3 = *(const bf16x8*)(qp + (size_t)qrow * DKk + 48 + hi * 8);

  const int krow = t >> 3, kch = t & 7;  // K staging: 64 rows x 8 chunks
  const int vkey = t & 63, vdg = w;      // V staging: key = lane, dk-group = w

  f32x16 ctx0, ctx1;
#pragma unroll
  for (int r = 0; r < 16; r++) { ctx0[r] = 0.f; ctx1[r] = 0.f; }
  float m_run = -1e30f, l_run = 0.f;

  // prologue: stage tile 0
  bf16x8 kreg = *(const bf16x8*)(kp + (size_t)krow * DKk + kch * 8);
  bf16x8 vreg = *(const bf16x8*)(vp + (size_t)vkey * DKk + vdg * 8);
  *(bf16x4*)&Ks[0][krow][kch * 8] = __builtin_shufflevector(kreg, kreg, 0, 1, 2, 3);
  *(bf16x4*)&Ks[0][krow][kch * 8 + 4] = __builtin_shufflevector(kreg, kreg, 4, 5, 6, 7);
#pragma unroll
  for (int e = 0; e < 8; e++) Vt[0][vdg * 8 + e][vkey] = vreg[e];
  __syncthreads();

  for (int it = 0; it < Ss / 64; ++it) {
    const int cb = it & 1;
    if (it < Ss / 64 - 1) {  // issue next-tile global loads early (T14)
      const size_t off = (size_t)(it + 1) * 64 * DKk;
      kreg = *(const bf16x8*)(kp + off + (size_t)krow * DKk + kch * 8);
      vreg = *(const bf16x8*)(vp + off + (size_t)vkey * DKk + vdg * 8);
    }

    // QK^T (swapped): st[key-group][16 regs], accumulate over 4 k-steps
    f32x16 st0, st1;
#pragma unroll
    for (int r = 0; r < 16; r++) { st0[r] = 0.f; st1[r] = 0.f; }
#pragma unroll
    for (int s = 0; s < 4; s++) {
      bf16x4 a0 = *(const bf16x4*)&Ks[cb][ql][s * 16 + hi * 8];
      bf16x4 a1 = *(const bf16x4*)&Ks[cb][ql][s * 16 + hi * 8 + 4];
      bf16x8 af = __builtin_shufflevector(a0, a1, 0, 1, 2, 3, 4, 5, 6, 7);
      bf16x4 c0 = *(const bf16x4*)&Ks[cb][32 + ql][s * 16 + hi * 8];
      bf16x4 c1 = *(const bf16x4*)&Ks[cb][32 + ql][s * 16 + hi * 8 + 4];
      bf16x8 af2 = __builtin_shufflevector(c0, c1, 0, 1, 2, 3, 4, 5, 6, 7);
      bf16x8 qf = (s == 0) ? qf0 : ((s == 1) ? qf1 : ((s == 2) ? qf2 : qf3));
      st0 = MFMA32(af, qf, st0);
      st1 = MFMA32(af2, qf, st1);
    }

    // online softmax (exp2 domain), defer-max THR=8
    float mx = st0[0];
#pragma unroll
    for (int r = 1; r < 16; r++) mx = fmaxf(mx, st0[r]);
#pragma unroll
    for (int r = 0; r < 16; r++) mx = fmaxf(mx, st1[r]);
    mx = fmaxf(mx, __shfl_xor(mx, 32));
    if (__any(mx > m_run + 8.0f)) {
      float mn = fmaxf(m_run, mx);
      float sc = fast_exp2(m_run - mn);
      l_run *= sc;
#pragma unroll
      for (int r = 0; r < 16; r++) { ctx0[r] *= sc; ctx1[r] *= sc; }
      m_run = mn;
    }
    float p0[16], p1[16];
    float ps = 0.f;
#pragma unroll
    for (int r = 0; r < 16; r++) { p0[r] = fast_exp2(st0[r] - m_run); ps += p0[r]; }
#pragma unroll
    for (int r = 0; r < 16; r++) { p1[r] = fast_exp2(st1[r] - m_run); ps += p1[r]; }
    ps += __shfl_xor(ps, 32);
    l_run += ps;

    // P -> bf16 B-fragments via cvt_pk + permlane32_swap (T12)
    union U { unsigned u[4]; bf16x8 v; };
    U F00, F01, F10, F11;
    {
      unsigned x0 = cvtpk(p0[0], p0[1]), y0 = cvtpk(p0[4], p0[5]); plswap(x0, y0);
      unsigned x1 = cvtpk(p0[2], p0[3]), y1 = cvtpk(p0[6], p0[7]); plswap(x1, y1);
      F00.u[0] = x0; F00.u[1] = x1; F00.u[2] = y0; F00.u[3] = y1;
      unsigned x2 = cvtpk(p0[8], p0[9]), y2 = cvtpk(p0[12], p0[13]); plswap(x2, y2);
      unsigned x3 = cvtpk(p0[10], p0[11]), y3 = cvtpk(p0[14], p0[15]); plswap(x3, y3);
      F01.u[0] = x2; F01.u[1] = x3; F01.u[2] = y2; F01.u[3] = y3;
      unsigned x4 = cvtpk(p1[0], p1[1]), y4 = cvtpk(p1[4], p1[5]); plswap(x4, y4);
      unsigned x5 = cvtpk(p1[2], p1[3]), y5 = cvtpk(p1[6], p1[7]); plswap(x5, y5);
      F10.u[0] = x4; F10.u[1] = x5; F10.u[2] = y4; F10.u[3] = y5;
      unsigned x6 = cvtpk(p1[8], p1[9]), y6 = cvtpk(p1[12], p1[13]); plswap(x6, y6);
      unsigned x7 = cvtpk(p1[10], p1[11]), y7 = cvtpk(p1[14], p1[15]); plswap(x7, y7);
      F11.u[0] = x6; F11.u[1] = x7; F11.u[2] = y6; F11.u[3] = y7;
    }

    // PV (swapped): ctxT[dk][q] += Vt-rows x P
    auto rdv = [&](int mtrow, int col) -> bf16x8 {
      bf16x4 lo4 = *(const bf16x4*)&Vt[cb][mtrow + ql][col + hi * 8];
      bf16x4 hi4 = *(const bf16x4*)&Vt[cb][mtrow + ql][col + hi * 8 + 4];
      return __builtin_shufflevector(lo4, hi4, 0, 1, 2, 3, 4, 5, 6, 7);
    };
    ctx0 = MFMA32(rdv(0, 0), F00.v, ctx0);
    ctx0 = MFMA32(rdv(0, 16), F01.v, ctx0);
    ctx0 = MFMA32(rdv(0, 32), F10.v, ctx0);
    ctx0 = MFMA32(rdv(0, 48), F11.v, ctx0);
    ctx1 = MFMA32(rdv(32, 0), F00.v, ctx1);
    ctx1 = MFMA32(rdv(32, 16), F01.v, ctx1);
    ctx1 = MFMA32(rdv(32, 32), F10.v, ctx1);
    ctx1 = MFMA32(rdv(32, 48), F11.v, ctx1);

    // write next tile to the other buffer (waits vmcnt via data dep)
    if (it < Ss / 64 - 1) {
      *(bf16x4*)&Ks[cb ^ 1][krow][kch * 8] =
          __builtin_shufflevector(kreg, kreg, 0, 1, 2, 3);
      *(bf16x4*)&Ks[cb ^ 1][krow][kch * 8 + 4] =
          __builtin_shufflevector(kreg, kreg, 4, 5, 6, 7);
#pragma unroll
      for (int e = 0; e < 8; e++) Vt[cb ^ 1][vdg * 8 + e][vkey] = vreg[e];
    }
    __syncthreads();
  }

  // finalize: divide by l, write z[b][s][h*64 + dk] (8B stores)
  float inv = 1.f / l_run;
  const int bI = bh >> 3, hh = bh & 7;
  bf16_t* zr = zout + ((size_t)bI * Ss + qrow) * Ee + hh * 64;
#pragma unroll
  for (int a = 0; a < 4; a++) {
    bf16x4 o0, o1;
#pragma unroll
    for (int b2 = 0; b2 < 4; b2++) {
      o0[b2] = f2bf(ctx0[a * 4 + b2] * inv);
      o1[b2] = f2bf(ctx1[a * 4 + b2] * inv);
    }
    *(bf16x4*)(zr + a * 8 + hi * 4) = o0;
    *(bf16x4*)(zr + 32 + a * 8 + hi * 4) = o1;
  }
}

// ---------------------------------------------------------------------------
// LayerNorm over E=512. One wave per row. grid (2048), 256 threads.
// ---------------------------------------------------------------------------
__global__ __launch_bounds__(256) void ln_k(
    const float* __restrict__ x, const float* __restrict__ gamma,
    const float* __restrict__ beta, float* __restrict__ out) {
  int row = blockIdx.x * 4 + (threadIdx.x >> 6);
  int lane = threadIdx.x & 63;
  const float* xr = x + (size_t)row * Ee;
  float4 v0 = *(const float4*)(xr + lane * 8);
  float4 v1 = *(const float4*)(xr + lane * 8 + 4);
  float s = v0.x + v0.y + v0.z + v0.w + v1.x + v1.y + v1.z + v1.w;
  float ss = v0.x * v0.x + v0.y * v0.y + v0.z * v0.z + v0.w * v0.w +
             v1.x * v1.x + v1.y * v1.y + v1.z * v1.z + v1.w * v1.w;
#pragma unroll
  for (int off = 32; off >= 1; off >>= 1) {
    s += __shfl_xor(s, off);
    ss += __shfl_xor(ss, off);
  }
  float mean = s * (1.f / 512.f);
  float var = ss * (1.f / 512.f) - mean * mean;
  float inv = rsqrtf(var + 1e-5f);
  float4 g0 = *(const float4*)(gamma + lane * 8);
  float4 g1 = *(const float4*)(gamma + lane * 8 + 4);
  float4 b0 = *(const float4*)(beta + lane * 8);
  float4 b1 = *(const float4*)(beta + lane * 8 + 4);
  float4 o0, o1;
  o0.x = (v0.x - mean) * inv * g0.x + b0.x;
  o0.y = (v0.y - mean) * inv * g0.y + b0.y;
  o0.z = (v0.z - mean) * inv * g0.z + b0.z;
  o0.w = (v0.w - mean) * inv * g0.w + b0.w;
  o1.x = (v1.x - mean) * inv * g1.x + b1.x;
  o1.y = (v1.y - mean) * inv * g1.y + b1.y;
  o1.z = (v1.z - mean) * inv * g1.z + b1.z;
  o1.w = (v1.w - mean) * inv * g1.w + b1.w;
  float* orow = out + (size_t)row * Ee;
  *(float4*)(orow + lane * 8) = o0;
  *(float4*)(orow + lane * 8 + 4) = o1;
}

// ---------------------------------------------------------------------------
extern "C" void kernel_launch(void* const* d_in, const int* in_sizes, int n_in,
                              void* d_out, int out_size, void* d_ws, size_t ws_size,
                              hipStream_t stream) {
  const float* Q = (const float*)d_in[0];
  const float* K = (const float*)d_in[1];
  const float* V = (const float*)d_in[2];
  const float* Wq = (const float*)d_in[3];
  const float* bq = (const float*)d_in[4];
  const float* Wk = (const float*)d_in[5];
  const float* bk = (const float*)d_in[6];
  const float* Wv = (const float*)d_in[7];
  const float* bv = (const float*)d_in[8];
  const float* Wf = (const float*)d_in[9];
  const float* bfb = (const float*)d_in[10];
  const float* gamma = (const float*)d_in[11];
  const float* beta = (const float*)d_in[12];
  float* out = (float*)d_out;

  // workspace layout (bf16 elements unless noted), total 52,428,800 B:
  //   Wt   : 3*512*512          = 786432
  //   Wft  : 512*512            = 262144
  //   qkv  : 3*4*8*2048*64      = 12582912   (later reused as x, fp32 16MB)
  //   sA   : 3*8192*512         = 12582912   (Qb/Kb/Vb; later reused as z)
  bf16_t* Wt = (bf16_t*)d_ws;
  bf16_t* Wft = Wt + 3 * Ee * Ee;
  bf16_t* qkv = Wft + Ee * Ee;
  bf16_t* sA = qkv + (size_t)3 * Bb * Hh * Ss * DKk;
  bf16_t* z = sA;          // attn output overlays Qb (dead after proj)
  float* x = (float*)qkv;  // final-GEMM output overlays qkv (dead after attn)

  cvt_k<<<dim3(6144), dim3(256), 0, stream>>>(Q, K, V, sA);
  pack_weights_k<<<dim3(8, 32), dim3(256), 0, stream>>>(Wq, Wk, Wv, Wf, Wt, Wft);
  proj_gemm_k<<<dim3(4, 64, 3), dim3(256), 0, stream>>>(sA, Wt, bq, bk, bv, qkv);
  attn_k<<<dim3(8, 32), dim3(512), 0, stream>>>(qkv, z);
  final_gemm_k<<<dim3(4, 64), dim3(256), 0, stream>>>(z, Wft, bfb, Q, x);
  ln_k<<<dim3(2048), dim3(256), 0, stream>>>(x, gamma, beta, out);
}

// Round 6
// 207.967 us; speedup vs baseline: 1.5035x; 1.0158x over previous
//
#include <hip/hip_runtime.h>
#include <hip/hip_bf16.h>

#define Bb 4
#define Ss 2048
#define Ee 512
#define Hh 8
#define DKk 64
// M = Bb*Ss = 8192

typedef __bf16 bf16_t;
typedef bf16_t bf16x8 __attribute__((ext_vector_type(8)));
typedef bf16_t bf16x4 __attribute__((ext_vector_type(4)));
typedef float f32x4 __attribute__((ext_vector_type(4)));
typedef float f32x16 __attribute__((ext_vector_type(16)));

#define MFMA16(a, b, c) __builtin_amdgcn_mfma_f32_16x16x32_bf16(a, b, c, 0, 0, 0)
#define MFMA32(a, b, c) __builtin_amdgcn_mfma_f32_32x32x16_bf16(a, b, c, 0, 0, 0)

#define GLOAD16(src, dst)                                          \
  __builtin_amdgcn_global_load_lds(                                \
      (const __attribute__((address_space(1))) void*)(src),        \
      (__attribute__((address_space(3))) void*)(dst), 16, 0, 0)

#define LO4(v) __builtin_shufflevector(v, v, 0, 1, 2, 3)
#define HI4(v) __builtin_shufflevector(v, v, 4, 5, 6, 7)

static __device__ __forceinline__ bf16_t f2bf(float f) { return (bf16_t)f; }

static __device__ __forceinline__ float fast_exp2(float x) {
#if __has_builtin(__builtin_amdgcn_exp2f)
  return __builtin_amdgcn_exp2f(x);
#else
  return exp2f(x);
#endif
}

static __device__ __forceinline__ unsigned cvtpk(float lo, float hi) {
  unsigned r;
  asm("v_cvt_pk_bf16_f32 %0, %1, %2" : "=v"(r) : "v"(lo), "v"(hi));
  return r;
}
// v_permlane32_swap_b32: A[32:63] <-> B[0:31].
static __device__ __forceinline__ void plswap(unsigned& a, unsigned& b) {
  asm("v_permlane32_swap_b32 %0, %1" : "+v"(a), "+v"(b));
}

// ---------------------------------------------------------------------------
// fp32 -> bf16 convert: Q,K,V -> Qb,Kb,Vb (contiguous at dst).
// ---------------------------------------------------------------------------
__global__ __launch_bounds__(256) void cvt_k(const float* __restrict__ Q,
                                             const float* __restrict__ K,
                                             const float* __restrict__ V,
                                             bf16_t* __restrict__ dst) {
  int which = blockIdx.x >> 11;
  int bi = blockIdx.x & 2047;
  const float* src = (which == 0) ? Q : ((which == 1) ? K : V);
  bf16_t* d = dst + (size_t)which * ((size_t)Bb * Ss * Ee);
  size_t idx = ((size_t)bi * 256 + threadIdx.x) * 8;
  float4 a = *(const float4*)(src + idx);
  float4 b = *(const float4*)(src + idx + 4);
  bf16x8 o;
  o[0] = f2bf(a.x); o[1] = f2bf(a.y); o[2] = f2bf(a.z); o[3] = f2bf(a.w);
  o[4] = f2bf(b.x); o[5] = f2bf(b.y); o[6] = f2bf(b.z); o[7] = f2bf(b.w);
  *(bf16x8*)(d + idx) = o;
}

// ---------------------------------------------------------------------------
// Pack: transpose + fp32->bf16 weights.
//  Wt[mat][n = h*64+d][k = e] = W_mat[h][e][d]   (mat = 0,1,2 : Wq,Wk,Wv)
//  Wft[f][e] = Wf[e][f]
// ---------------------------------------------------------------------------
__global__ __launch_bounds__(256) void pack_weights_k(
    const float* __restrict__ Wq, const float* __restrict__ Wk,
    const float* __restrict__ Wv, const float* __restrict__ Wf,
    bf16_t* __restrict__ Wt, bf16_t* __restrict__ Wft) {
  __shared__ float tile[64][65];
  int t = threadIdx.x;
  int y = blockIdx.y;
  const float* sp;
  bf16_t* dp;
  int sR, r0, c0;
  if (y < 24) {
    int mat = y >> 3, h = y & 7;
    const float* W = (mat == 0) ? Wq : ((mat == 1) ? Wk : Wv);
    sp = W + (size_t)h * (Ee * DKk);
    sR = 64;
    dp = Wt + (size_t)mat * (Ee * Ee) + (size_t)(h * 64) * Ee;
    r0 = blockIdx.x * 64;
    c0 = 0;
  } else {
    sp = Wf;
    sR = 512;
    dp = Wft;
    r0 = blockIdx.x * 64;
    c0 = (y - 24) * 64;
  }
  int lr = t >> 2, seg = t & 3;
  const float* sprow = sp + (size_t)(r0 + lr) * sR + c0 + seg * 16;
  float4 f0 = ((const float4*)sprow)[0];
  float4 f1 = ((const float4*)sprow)[1];
  float4 f2 = ((const float4*)sprow)[2];
  float4 f3 = ((const float4*)sprow)[3];
  tile[lr][seg * 16 + 0] = f0.x;  tile[lr][seg * 16 + 1] = f0.y;
  tile[lr][seg * 16 + 2] = f0.z;  tile[lr][seg * 16 + 3] = f0.w;
  tile[lr][seg * 16 + 4] = f1.x;  tile[lr][seg * 16 + 5] = f1.y;
  tile[lr][seg * 16 + 6] = f1.z;  tile[lr][seg * 16 + 7] = f1.w;
  tile[lr][seg * 16 + 8] = f2.x;  tile[lr][seg * 16 + 9] = f2.y;
  tile[lr][seg * 16 + 10] = f2.z; tile[lr][seg * 16 + 11] = f2.w;
  tile[lr][seg * 16 + 12] = f3.x; tile[lr][seg * 16 + 13] = f3.y;
  tile[lr][seg * 16 + 14] = f3.z; tile[lr][seg * 16 + 15] = f3.w;
  __syncthreads();
  bf16x8 o0, o1;
#pragma unroll
  for (int i = 0; i < 8; i++) {
    o0[i] = f2bf(tile[seg * 16 + i][lr]);
    o1[i] = f2bf(tile[seg * 16 + 8 + i][lr]);
  }
  bf16_t* dst = dp + (size_t)(c0 + lr) * Ee + r0 + seg * 16;
  *(bf16x8*)dst = o0;
  *(bf16x8*)(dst + 8) = o1;
}

// ---------------------------------------------------------------------------
// V transpose: vtG[bh][dk][s] = qkvV[bh][s][dk].  64x64 LDS tiles.
// grid (32 sblocks, 32 bh), 256 threads.
// ---------------------------------------------------------------------------
__global__ __launch_bounds__(256) void vt_k(const bf16_t* __restrict__ vsrc,
                                            bf16_t* __restrict__ vtG) {
  __shared__ bf16_t tile[64][68];
  const int t = threadIdx.x;
  const int bh = blockIdx.y;
  const int s0 = blockIdx.x * 64;
  const bf16_t* vp = vsrc + (size_t)bh * (Ss * DKk);
  const int r = t >> 2, seg = t & 3;
  // load 64 s-rows x 64 dk
  const bf16_t* src = vp + (size_t)(s0 + r) * DKk + seg * 16;
  bf16x8 a = ((const bf16x8*)src)[0];
  bf16x8 b = ((const bf16x8*)src)[1];
  bf16_t* ld = &tile[r][seg * 16];
  *(bf16x4*)(ld + 0) = LO4(a); *(bf16x4*)(ld + 4) = HI4(a);
  *(bf16x4*)(ld + 8) = LO4(b); *(bf16x4*)(ld + 12) = HI4(b);
  __syncthreads();
  // write transposed: dk-row r, s-chunk seg*16
  bf16x8 o0, o1;
#pragma unroll
  for (int j = 0; j < 8; j++) {
    o0[j] = tile[seg * 16 + j][r];
    o1[j] = tile[seg * 16 + 8 + j][r];
  }
  bf16_t* dst = vtG + (size_t)bh * ((size_t)DKk * Ss) + (size_t)r * Ss + s0 + seg * 16;
  *(bf16x8*)dst = o0;
  *(bf16x8*)(dst + 8) = o1;
}

// ---------------------------------------------------------------------------
// Projection GEMM (operand-swapped): D[n][m] = sum_e Wt[n][e] * Xb[m][e]
// 128x128 tile, BK=64, global_load_lds + XOR-chunk swizzle; T1 XCD swizzle.
// ---------------------------------------------------------------------------
__global__ __launch_bounds__(256) void proj_gemm_k(
    const bf16_t* __restrict__ Xb3, const bf16_t* __restrict__ Wt,
    const float* __restrict__ bq, const float* __restrict__ bk,
    const float* __restrict__ bv, bf16_t* __restrict__ qkv) {
  __shared__ bf16_t As[128 * 64];
  __shared__ bf16_t Bs[128 * 64];
  const int t = threadIdx.x;
  const int zb = blockIdx.z;
  const bf16_t* Ap = Wt + (size_t)zb * (Ee * Ee);
  const bf16_t* Bp = Xb3 + (size_t)zb * ((size_t)Bb * Ss * Ee);
  const float* bias = (zb == 0) ? bq : ((zb == 1) ? bk : bv);
  bf16_t* Outp = qkv + (size_t)zb * ((size_t)Bb * Hh * Ss * DKk);
  const float scl = (zb == 0) ? 0.18033688f : 1.0f;  // 0.125 * log2(e) for q
  // T1: bijective XCD-chunk swizzle over the 256 (x,y) tiles (256 % 8 == 0)
  const int id = blockIdx.x + (blockIdx.y << 2);
  const int nid = (id & 7) * 32 + (id >> 3);
  const int n0 = (nid & 3) * 128;
  const int m0 = (nid >> 2) * 128;
  const int lane = t & 63, w = t >> 6;
  const int wn = w >> 1, wm = w & 1;
  const int rsel = lane & 15, grp = lane >> 4;
  const int wbase = (t & ~63);

  f32x4 acc[4][4];
#pragma unroll
  for (int ni = 0; ni < 4; ni++)
#pragma unroll
    for (int mi = 0; mi < 4; mi++) acc[ni][mi] = (f32x4){0.f, 0.f, 0.f, 0.f};

  for (int k0 = 0; k0 < Ee; k0 += 64) {
#pragma unroll
    for (int i = 0; i < 4; i++) {
      int slot = i * 256 + t;
      int row = slot >> 3;
      int g = (slot & 7) ^ (row & 7);
      GLOAD16(Ap + (size_t)(n0 + row) * Ee + k0 + g * 8,
              As + (size_t)(i * 256 + wbase) * 8);
      GLOAD16(Bp + (size_t)(m0 + row) * Ee + k0 + g * 8,
              Bs + (size_t)(i * 256 + wbase) * 8);
    }
    __syncthreads();
#pragma unroll
    for (int kk = 0; kk < 2; kk++) {
      bf16x8 af[4], bff[4];
#pragma unroll
      for (int ni = 0; ni < 4; ni++) {
        int arow = wn * 64 + ni * 16 + rsel;
        int c = ((kk * 4 + grp) ^ (arow & 7)) * 8;
        af[ni] = *(const bf16x8*)&As[arow * 64 + c];
      }
#pragma unroll
      for (int mi = 0; mi < 4; mi++) {
        int brow = wm * 64 + mi * 16 + rsel;
        int c = ((kk * 4 + grp) ^ (brow & 7)) * 8;
        bff[mi] = *(const bf16x8*)&Bs[brow * 64 + c];
      }
#pragma unroll
      for (int ni = 0; ni < 4; ni++)
#pragma unroll
        for (int mi = 0; mi < 4; mi++)
          acc[ni][mi] = MFMA16(af[ni], bff[mi], acc[ni][mi]);
    }
    __syncthreads();
  }

#pragma unroll
  for (int ni = 0; ni < 4; ni++) {
    int nb = n0 + wn * 64 + ni * 16 + grp * 4;
    float4 b4 = *(const float4*)(bias + nb);
    const float* b4p = (const float*)&b4;
    int hh = nb >> 6, dd = nb & 63;
#pragma unroll
    for (int mi = 0; mi < 4; mi++) {
      int m = m0 + wm * 64 + mi * 16 + rsel;
      int bI = m >> 11, sI = m & 2047;
      bf16x4 o;
#pragma unroll
      for (int r = 0; r < 4; r++)
        o[r] = f2bf((acc[ni][mi][r] + b4p[r]) * scl);
      *(bf16x4*)(Outp + (((size_t)(bI * Hh + hh)) * Ss + sI) * DKk + dd) = o;
    }
  }
}

// ---------------------------------------------------------------------------
// Final GEMM (operand-swapped): D[f][m] = sum_e Wft[f][e] * z[m][e]
// Epilogue: x[m][f..f+4] = acc + bf + Qres (fp32, 16B stores). T1 swizzle.
// ---------------------------------------------------------------------------
__global__ __launch_bounds__(256) void final_gemm_k(
    const bf16_t* __restrict__ zin, const bf16_t* __restrict__ Wft,
    const float* __restrict__ bfb, const float* __restrict__ Qres,
    float* __restrict__ x) {
  __shared__ bf16_t As[128 * 64];
  __shared__ bf16_t Bs[128 * 64];
  const int t = threadIdx.x;
  const int id = blockIdx.x + (blockIdx.y << 2);
  const int nid = (id & 7) * 32 + (id >> 3);
  const int n0 = (nid & 3) * 128;
  const int m0 = (nid >> 2) * 128;
  const int lane = t & 63, w = t >> 6;
  const int wn = w >> 1, wm = w & 1;
  const int rsel = lane & 15, grp = lane >> 4;
  const int wbase = (t & ~63);

  f32x4 acc[4][4];
#pragma unroll
  for (int ni = 0; ni < 4; ni++)
#pragma unroll
    for (int mi = 0; mi < 4; mi++) acc[ni][mi] = (f32x4){0.f, 0.f, 0.f, 0.f};

  for (int k0 = 0; k0 < Ee; k0 += 64) {
#pragma unroll
    for (int i = 0; i < 4; i++) {
      int slot = i * 256 + t;
      int row = slot >> 3;
      int g = (slot & 7) ^ (row & 7);
      GLOAD16(Wft + (size_t)(n0 + row) * Ee + k0 + g * 8,
              As + (size_t)(i * 256 + wbase) * 8);
      GLOAD16(zin + (size_t)(m0 + row) * Ee + k0 + g * 8,
              Bs + (size_t)(i * 256 + wbase) * 8);
    }
    __syncthreads();
#pragma unroll
    for (int kk = 0; kk < 2; kk++) {
      bf16x8 af[4], bff[4];
#pragma unroll
      for (int ni = 0; ni < 4; ni++) {
        int arow = wn * 64 + ni * 16 + rsel;
        int c = ((kk * 4 + grp) ^ (arow & 7)) * 8;
        af[ni] = *(const bf16x8*)&As[arow * 64 + c];
      }
#pragma unroll
      for (int mi = 0; mi < 4; mi++) {
        int brow = wm * 64 + mi * 16 + rsel;
        int c = ((kk * 4 + grp) ^ (brow & 7)) * 8;
        bff[mi] = *(const bf16x8*)&Bs[brow * 64 + c];
      }
#pragma unroll
      for (int ni = 0; ni < 4; ni++)
#pragma unroll
        for (int mi = 0; mi < 4; mi++)
          acc[ni][mi] = MFMA16(af[ni], bff[mi], acc[ni][mi]);
    }
    __syncthreads();
  }

#pragma unroll
  for (int ni = 0; ni < 4; ni++) {
    int nb = n0 + wn * 64 + ni * 16 + grp * 4;
    float4 b4 = *(const float4*)(bfb + nb);
#pragma unroll
    for (int mi = 0; mi < 4; mi++) {
      int m = m0 + wm * 64 + mi * 16 + rsel;
      float4 q4 = *(const float4*)(Qres + (size_t)m * Ee + nb);
      float4 o;
      o.x = acc[ni][mi][0] + b4.x + q4.x;
      o.y = acc[ni][mi][1] + b4.y + q4.y;
      o.z = acc[ni][mi][2] + b4.z + q4.z;
      o.w = acc[ni][mi][3] + b4.w + q4.w;
      *(float4*)(x + (size_t)m * Ee + nb) = o;
    }
  }
}

// ---------------------------------------------------------------------------
// Flash attention, 32x32 swapped-operand + in-block KV-split.
// 8 waves = 4 q-subblocks x 2 KV-halves; grid (16, 32); KV tile = 64.
// Wave (qsub, half): q-rows [blk*128 + qsub*32, +32), keys [half*1024, +1024).
// End: flash-merge of the two halves through LDS (aliased over K/V bufs).
// q pre-scaled by 0.125*log2(e) -> softmax in exp2 domain.
// ---------------------------------------------------------------------------
__global__ __launch_bounds__(512, 4) void attn_k(const bf16_t* __restrict__ qkv,
                                                 const bf16_t* __restrict__ vtG,
                                                 bf16_t* __restrict__ zout) {
  const size_t HS = (size_t)Bb * Hh * Ss * DKk;
  __shared__ __align__(16) unsigned char smem_raw[2 * 34816];
  bf16_t (*Ks)[2][64][68] = reinterpret_cast<bf16_t (*)[2][64][68]>(smem_raw);
  bf16_t (*Vt)[2][64][68] = reinterpret_cast<bf16_t (*)[2][64][68]>(smem_raw + 34816);
  const int t = threadIdx.x, w = t >> 6, lane = t & 63;
  const int qsub = w >> 1, half = w & 1;
  const int ql = lane & 31, hi = lane >> 5;
  const int bh = blockIdx.y;
  const bf16_t* qp = qkv + (size_t)bh * (Ss * DKk);
  const bf16_t* kp = qp + HS;
  const bf16_t* vt = vtG + (size_t)bh * ((size_t)DKk * Ss);
  const int qrow = blockIdx.x * 128 + qsub * 32 + ql;

  // Q B-fragments (hoisted): k-dim = dk, col = q
  bf16x8 qf0 = *(const bf16x8*)(qp + (size_t)qrow * DKk + 0 + hi * 8);
  bf16x8 qf1 = *(const bf16x8*)(qp + (size_t)qrow * DKk + 16 + hi * 8);
  bf16x8 qf2 = *(const bf16x8*)(qp + (size_t)qrow * DKk + 32 + hi * 8);
  bf16x8 qf3 = *(const bf16x8*)(qp + (size_t)qrow * DKk + 48 + hi * 8);

  // staging role within the half's 4 waves: sid in [0,256)
  const int sid = qsub * 64 + lane;
  const int srow = sid >> 2, sseg = sid & 3;
  const int koff0 = half * (Ss / 2);

  f32x16 ctx0, ctx1;
#pragma unroll
  for (int r = 0; r < 16; r++) { ctx0[r] = 0.f; ctx1[r] = 0.f; }
  float m_run = -1e30f, l_run = 0.f;

  // prologue: stage tile 0 of this half
  {
    const bf16_t* ksrc = kp + (size_t)(koff0 + srow) * DKk + sseg * 16;
    bf16x8 ka = ((const bf16x8*)ksrc)[0], kb = ((const bf16x8*)ksrc)[1];
    const bf16_t* vsrc = vt + (size_t)srow * Ss + koff0 + sseg * 16;
    bf16x8 va = ((const bf16x8*)vsrc)[0], vb = ((const bf16x8*)vsrc)[1];
    bf16_t* kd = &Ks[half][0][srow][sseg * 16];
    *(bf16x4*)(kd + 0) = LO4(ka); *(bf16x4*)(kd + 4) = HI4(ka);
    *(bf16x4*)(kd + 8) = LO4(kb); *(bf16x4*)(kd + 12) = HI4(kb);
    bf16_t* vd = &Vt[half][0][srow][sseg * 16];
    *(bf16x4*)(vd + 0) = LO4(va); *(bf16x4*)(vd + 4) = HI4(va);
    *(bf16x4*)(vd + 8) = LO4(vb); *(bf16x4*)(vd + 12) = HI4(vb);
  }
  __syncthreads();

  const int NT = (Ss / 2) / 64;  // 16 tiles per half
  bf16x8 pk0, pk1, pv0, pv1;
  for (int it = 0; it < NT; ++it) {
    const int cb = it & 1;
    if (it < NT - 1) {  // T14: issue next-tile global loads early
      const int k0 = koff0 + (it + 1) * 64;
      const bf16_t* ksrc = kp + (size_t)(k0 + srow) * DKk + sseg * 16;
      pk0 = ((const bf16x8*)ksrc)[0]; pk1 = ((const bf16x8*)ksrc)[1];
      const bf16_t* vsrc = vt + (size_t)srow * Ss + k0 + sseg * 16;
      pv0 = ((const bf16x8*)vsrc)[0]; pv1 = ((const bf16x8*)vsrc)[1];
    }

    // QK^T (swapped): st[key-group][16 regs], accumulate over 4 k-steps
    f32x16 st0, st1;
#pragma unroll
    for (int r = 0; r < 16; r++) { st0[r] = 0.f; st1[r] = 0.f; }
    __builtin_amdgcn_s_setprio(1);
#pragma unroll
    for (int s = 0; s < 4; s++) {
      bf16x4 a0 = *(const bf16x4*)&Ks[half][cb][ql][s * 16 + hi * 8];
      bf16x4 a1 = *(const bf16x4*)&Ks[half][cb][ql][s * 16 + hi * 8 + 4];
      bf16x8 af = __builtin_shufflevector(a0, a1, 0, 1, 2, 3, 4, 5, 6, 7);
      bf16x4 c0 = *(const bf16x4*)&Ks[half][cb][32 + ql][s * 16 + hi * 8];
      bf16x4 c1 = *(const bf16x4*)&Ks[half][cb][32 + ql][s * 16 + hi * 8 + 4];
      bf16x8 af2 = __builtin_shufflevector(c0, c1, 0, 1, 2, 3, 4, 5, 6, 7);
      bf16x8 qf = (s == 0) ? qf0 : ((s == 1) ? qf1 : ((s == 2) ? qf2 : qf3));
      st0 = MFMA32(af, qf, st0);
      st1 = MFMA32(af2, qf, st1);
    }
    __builtin_amdgcn_s_setprio(0);

    // online softmax (exp2 domain), defer-max THR=8
    float mx = st0[0];
#pragma unroll
    for (int r = 1; r < 16; r++) mx = fmaxf(mx, st0[r]);
#pragma unroll
    for (int r = 0; r < 16; r++) mx = fmaxf(mx, st1[r]);
    mx = fmaxf(mx, __shfl_xor(mx, 32));
    if (__any(mx > m_run + 8.0f)) {
      float mn = fmaxf(m_run, mx);
      float sc = fast_exp2(m_run - mn);
      l_run *= sc;
#pragma unroll
      for (int r = 0; r < 16; r++) { ctx0[r] *= sc; ctx1[r] *= sc; }
      m_run = mn;
    }
    float ps = 0.f;
#pragma unroll
    for (int r = 0; r < 16; r++) { st0[r] = fast_exp2(st0[r] - m_run); ps += st0[r]; }
#pragma unroll
    for (int r = 0; r < 16; r++) { st1[r] = fast_exp2(st1[r] - m_run); ps += st1[r]; }
    ps += __shfl_xor(ps, 32);
    l_run += ps;

    // P -> bf16 B-fragments via cvt_pk + permlane32_swap (T12)
    union U { unsigned u[4]; bf16x8 v; };
    U F00, F01, F10, F11;
    {
      unsigned x0 = cvtpk(st0[0], st0[1]), y0 = cvtpk(st0[4], st0[5]); plswap(x0, y0);
      unsigned x1 = cvtpk(st0[2], st0[3]), y1 = cvtpk(st0[6], st0[7]); plswap(x1, y1);
      F00.u[0] = x0; F00.u[1] = x1; F00.u[2] = y0; F00.u[3] = y1;
      unsigned x2 = cvtpk(st0[8], st0[9]), y2 = cvtpk(st0[12], st0[13]); plswap(x2, y2);
      unsigned x3 = cvtpk(st0[10], st0[11]), y3 = cvtpk(st0[14], st0[15]); plswap(x3, y3);
      F01.u[0] = x2; F01.u[1] = x3; F01.u[2] = y2; F01.u[3] = y3;
      unsigned x4 = cvtpk(st1[0], st1[1]), y4 = cvtpk(st1[4], st1[5]); plswap(x4, y4);
      unsigned x5 = cvtpk(st1[2], st1[3]), y5 = cvtpk(st1[6], st1[7]); plswap(x5, y5);
      F10.u[0] = x4; F10.u[1] = x5; F10.u[2] = y4; F10.u[3] = y5;
      unsigned x6 = cvtpk(st1[8], st1[9]), y6 = cvtpk(st1[12], st1[13]); plswap(x6, y6);
      unsigned x7 = cvtpk(st1[10], st1[11]), y7 = cvtpk(st1[14], st1[15]); plswap(x7, y7);
      F11.u[0] = x6; F11.u[1] = x7; F11.u[2] = y6; F11.u[3] = y7;
    }

    // PV (swapped): ctxT[dk][q] += Vt-rows x P
    auto rdv = [&](int mtrow, int col) -> bf16x8 {
      bf16x4 lo4 = *(const bf16x4*)&Vt[half][cb][mtrow + ql][col + hi * 8];
      bf16x4 hi4 = *(const bf16x4*)&Vt[half][cb][mtrow + ql][col + hi * 8 + 4];
      return __builtin_shufflevector(lo4, hi4, 0, 1, 2, 3, 4, 5, 6, 7);
    };
    __builtin_amdgcn_s_setprio(1);
    ctx0 = MFMA32(rdv(0, 0), F00.v, ctx0);
    ctx0 = MFMA32(rdv(0, 16), F01.v, ctx0);
    ctx0 = MFMA32(rdv(0, 32), F10.v, ctx0);
    ctx0 = MFMA32(rdv(0, 48), F11.v, ctx0);
    ctx1 = MFMA32(rdv(32, 0), F00.v, ctx1);
    ctx1 = MFMA32(rdv(32, 16), F01.v, ctx1);
    ctx1 = MFMA32(rdv(32, 32), F10.v, ctx1);
    ctx1 = MFMA32(rdv(32, 48), F11.v, ctx1);
    __builtin_amdgcn_s_setprio(0);

    // write next tile to the other buffer
    if (it < NT - 1) {
      bf16_t* kd = &Ks[half][cb ^ 1][srow][sseg * 16];
      *(bf16x4*)(kd + 0) = LO4(pk0); *(bf16x4*)(kd + 4) = HI4(pk0);
      *(bf16x4*)(kd + 8) = LO4(pk1); *(bf16x4*)(kd + 12) = HI4(pk1);
      bf16_t* vd = &Vt[half][cb ^ 1][srow][sseg * 16];
      *(bf16x4*)(vd + 0) = LO4(pv0); *(bf16x4*)(vd + 4) = HI4(pv0);
      *(bf16x4*)(vd + 8) = LO4(pv1); *(bf16x4*)(vd + 12) = HI4(pv1);
    }
    __syncthreads();
  }

  // merge the two KV-halves via LDS (aliased over Ks/Vt; safe after barrier).
  // layout (floats): ctx [256][33], then m[256], l[256].
  float* mr = (float*)smem_raw;
  const int msl = qsub * 64 + lane;
  float* cslot = mr + msl * 33;
  float* mym = mr + 8448;
  float* myl = mr + 8704;
  if (half == 1) {
#pragma unroll
    for (int r = 0; r < 16; r++) { cslot[r] = ctx0[r]; cslot[16 + r] = ctx1[r]; }
    mym[msl] = m_run;
    myl[msl] = l_run;
  }
  __syncthreads();
  if (half == 0) {
    float m1 = mym[msl], l1 = myl[msl];
    float mt = fmaxf(m_run, m1);
    float f0 = fast_exp2(m_run - mt), f1 = fast_exp2(m1 - mt);
    float inv = 1.f / (l_run * f0 + l1 * f1);
    const int bI = bh >> 3, hh = bh & 7;
    bf16_t* zr = zout + ((size_t)bI * Ss + qrow) * Ee + hh * 64;
#pragma unroll
    for (int a = 0; a < 4; a++) {
      bf16x4 o0, o1;
#pragma unroll
      for (int b2 = 0; b2 < 4; b2++) {
        o0[b2] = f2bf((ctx0[a * 4 + b2] * f0 + cslot[a * 4 + b2] * f1) * inv);
        o1[b2] = f2bf((ctx1[a * 4 + b2] * f0 + cslot[16 + a * 4 + b2] * f1) * inv);
      }
      *(bf16x4*)(zr + a * 8 + hi * 4) = o0;
      *(bf16x4*)(zr + 32 + a * 8 + hi * 4) = o1;
    }
  }
}

// ---------------------------------------------------------------------------
// LayerNorm over E=512. One wave per row. grid (2048), 256 threads.
// ---------------------------------------------------------------------------
__global__ __launch_bounds__(256) void ln_k(
    const float* __restrict__ x, const float* __restrict__ gamma,
    const float* __restrict__ beta, float* __restrict__ out) {
  int row = blockIdx.x * 4 + (threadIdx.x >> 6);
  int lane = threadIdx.x & 63;
  const float* xr = x + (size_t)row * Ee;
  float4 v0 = *(const float4*)(xr + lane * 8);
  float4 v1 = *(const float4*)(xr + lane * 8 + 4);
  float s = v0.x + v0.y + v0.z + v0.w + v1.x + v1.y + v1.z + v1.w;
  float ss = v0.x * v0.x + v0.y * v0.y + v0.z * v0.z + v0.w * v0.w +
             v1.x * v1.x + v1.y * v1.y + v1.z * v1.z + v1.w * v1.w;
#pragma unroll
  for (int off = 32; off >= 1; off >>= 1) {
    s += __shfl_xor(s, off);
    ss += __shfl_xor(ss, off);
  }
  float mean = s * (1.f / 512.f);
  float var = ss * (1.f / 512.f) - mean * mean;
  float inv = rsqrtf(var + 1e-5f);
  float4 g0 = *(const float4*)(gamma + lane * 8);
  float4 g1 = *(const float4*)(gamma + lane * 8 + 4);
  float4 b0 = *(const float4*)(beta + lane * 8);
  float4 b1 = *(const float4*)(beta + lane * 8 + 4);
  float4 o0, o1;
  o0.x = (v0.x - mean) * inv * g0.x + b0.x;
  o0.y = (v0.y - mean) * inv * g0.y + b0.y;
  o0.z = (v0.z - mean) * inv * g0.z + b0.z;
  o0.w = (v0.w - mean) * inv * g0.w + b0.w;
  o1.x = (v1.x - mean) * inv * g1.x + b1.x;
  o1.y = (v1.y - mean) * inv * g1.y + b1.y;
  o1.z = (v1.z - mean) * inv * g1.z + b1.z;
  o1.w = (v1.w - mean) * inv * g1.w + b1.w;
  float* orow = out + (size_t)row * Ee;
  *(float4*)(orow + lane * 8) = o0;
  *(float4*)(orow + lane * 8 + 4) = o1;
}

// ---------------------------------------------------------------------------
extern "C" void kernel_launch(void* const* d_in, const int* in_sizes, int n_in,
                              void* d_out, int out_size, void* d_ws, size_t ws_size,
                              hipStream_t stream) {
  const float* Q = (const float*)d_in[0];
  const float* K = (const float*)d_in[1];
  const float* V = (const float*)d_in[2];
  const float* Wq = (const float*)d_in[3];
  const float* bq = (const float*)d_in[4];
  const float* Wk = (const float*)d_in[5];
  const float* bk = (const float*)d_in[6];
  const float* Wv = (const float*)d_in[7];
  const float* bv = (const float*)d_in[8];
  const float* Wf = (const float*)d_in[9];
  const float* bfb = (const float*)d_in[10];
  const float* gamma = (const float*)d_in[11];
  const float* beta = (const float*)d_in[12];
  float* out = (float*)d_out;

  // workspace layout (bf16 elements), total 52,428,800 B:
  //   Wt   : 3*512*512          = 786432
  //   Wft  : 512*512            = 262144
  //   qkv  : 3*4*8*2048*64      = 12582912   (later reused as x, fp32 16MB)
  //   sA   : 3*8192*512         = 12582912   (Qb/Kb/Vb)
  //     z   overlays sA[0 .. 4M)      (Qb dead after proj)
  //     vtG overlays sA[4M .. 8M)     (Kb dead after proj)
  bf16_t* Wt = (bf16_t*)d_ws;
  bf16_t* Wft = Wt + 3 * Ee * Ee;
  bf16_t* qkv = Wft + Ee * Ee;
  bf16_t* sA = qkv + (size_t)3 * Bb * Hh * Ss * DKk;
  bf16_t* z = sA;
  bf16_t* vtG = sA + (size_t)Bb * Hh * Ss * DKk;
  float* x = (float*)qkv;  // final-GEMM output overlays qkv (dead after attn)

  cvt_k<<<dim3(6144), dim3(256), 0, stream>>>(Q, K, V, sA);
  pack_weights_k<<<dim3(8, 32), dim3(256), 0, stream>>>(Wq, Wk, Wv, Wf, Wt, Wft);
  proj_gemm_k<<<dim3(4, 64, 3), dim3(256), 0, stream>>>(sA, Wt, bq, bk, bv, qkv);
  vt_k<<<dim3(32, 32), dim3(256), 0, stream>>>(qkv + (size_t)2 * Bb * Hh * Ss * DKk, vtG);
  attn_k<<<dim3(16, 32), dim3(512), 0, stream>>>(qkv, vtG, z);
  final_gemm_k<<<dim3(4, 64), dim3(256), 0, stream>>>(z, Wft, bfb, Q, x);
  ln_k<<<dim3(2048), dim3(256), 0, stream>>>(x, gamma, beta, out);
}